// Round 17
// baseline (351.818 us; speedup 1.0000x reference)
//
#include <hip/hip_runtime.h>

typedef unsigned short u16;
typedef unsigned int u32;
typedef __bf16 bf16x8 __attribute__((ext_vector_type(8)));
typedef float f32x4 __attribute__((ext_vector_type(4)));
typedef float f32x16 __attribute__((ext_vector_type(16)));
typedef unsigned short us8 __attribute__((ext_vector_type(8)));
typedef unsigned short us4 __attribute__((ext_vector_type(4)));
typedef unsigned int u32x4 __attribute__((ext_vector_type(4)));

#define B_ 4
#define S_ 2048
#define D_ 1024
#define H_ 16
#define HD_ 64
#define QKS_ 3072  // row stride (elems) of the packed kqv buffer
#define EPS_ 1e-5f
#define SCALE_ (0.125f * 1.44269504088896341f)
#define THR_ 3.0f

__device__ __forceinline__ u16 f2bf(float f) {
  unsigned u = __builtin_bit_cast(unsigned, f);
  u = (u + 0x7FFFu + ((u >> 16) & 1u)) >> 16;
  return (u16)u;
}

__device__ __forceinline__ float gelu_f(float x) {
  float u = x * (2.3022388f + 0.10294971f * x * x);
  float te = __builtin_amdgcn_exp2f(u);
  return x - x * __builtin_amdgcn_rcpf(1.0f + te);
}

typedef const __attribute__((address_space(1))) unsigned int* gp1;
typedef __attribute__((address_space(3))) unsigned int* lp3;
__device__ __forceinline__ void gl_lds16(const void* g, void* l) {
  __builtin_amdgcn_global_load_lds((gp1)(unsigned long long)g,
                                   (lp3)(unsigned int)(unsigned long long)l,
                                   16, 0, 0);
}

__device__ __forceinline__ u32 cvtpk_bf16(float lo, float hi) {
  u32 d;
  asm("v_cvt_pk_bf16_f32 %0, %1, %2" : "=v"(d) : "v"(lo), "v"(hi));
  return d;
}
__device__ __forceinline__ void swap32(u32& a, u32& b) {
  asm("v_permlane32_swap_b32 %0, %1" : "+v"(a), "+v"(b));
}

__device__ __forceinline__ f32x16 zero16() {
  f32x16 z;
#pragma unroll
  for (int i = 0; i < 16; i++) z[i] = 0.f;
  return z;
}

// ---------------- weight transpose + f32->bf16 convert: W[K][N] -> Wt[N'][K] ---------------
__global__ __launch_bounds__(256) void wconv_kernel(const float* __restrict__ W,
                                                    u16* __restrict__ Wt,
                                                    int Kd, int N, int perm) {
  __shared__ u16 tile[32][33];
  int bid = blockIdx.x;
  int nbn = N >> 5;
  int tk = bid / nbn, tn = bid % nbn;
  int tx = threadIdx.x & 31, ty = threadIdx.x >> 5;
#pragma unroll
  for (int i = 0; i < 4; i++) {
    int r = ty + i * 8;
    tile[r][tx] = f2bf(W[(size_t)(tk * 32 + r) * N + tn * 32 + tx]);
  }
  __syncthreads();
#pragma unroll
  for (int i = 0; i < 4; i++) {
    int r = ty + i * 8;
    int orow = tn * 32 + r;
    int prow = perm ? ((orow % 3) << 10) + orow / 3 : orow;
    Wt[(size_t)prow * Kd + tk * 32 + tx] = tile[tx][r];
  }
}

// ---------------- V transpose: kqv V-block -> Vt [bh][64][S] --------------------------------
__global__ __launch_bounds__(256) void vtrans_kernel(const u16* __restrict__ kqv,
                                                     u16* __restrict__ Vt) {
  __shared__ u16 tile[64][72];
  int bh = blockIdx.x >> 5;
  int sb = blockIdx.x & 31;
  int b = bh >> 4, h = bh & 15;
  const u16* src = kqv + ((size_t)(b * S_ + sb * 64)) * QKS_ + 2048 + h * 64;
  int r = threadIdx.x >> 2, c0 = (threadIdx.x & 3) * 16;
  *(us8*)&tile[r][c0] = *(const us8*)(src + (size_t)r * QKS_ + c0);
  *(us8*)&tile[r][c0 + 8] = *(const us8*)(src + (size_t)r * QKS_ + c0 + 8);
  __syncthreads();
  u16* dst = Vt + (size_t)bh * HD_ * S_ + sb * 64;
  int hd = threadIdx.x >> 2;
  int s0 = (threadIdx.x & 3) * 16;
  us8 a, bb;
#pragma unroll
  for (int j = 0; j < 8; j++) a[j] = tile[s0 + j][hd];
#pragma unroll
  for (int j = 0; j < 8; j++) bb[j] = tile[s0 + 8 + j][hd];
  *(us8*)(dst + (size_t)hd * S_ + s0) = a;
  *(us8*)(dst + (size_t)hd * S_ + s0 + 8) = bb;
}

// ---------------- LayerNorm ------------------------------------------------------------------
__global__ __launch_bounds__(256) void ln_kernel(const float* __restrict__ x,
                                                 const float* __restrict__ w,
                                                 const float* __restrict__ b,
                                                 u16* __restrict__ out) {
  int row = blockIdx.x;
  int t = threadIdx.x;
  int lane = t & 63, wid = t >> 6;
  const float4* xr = (const float4*)(x + (size_t)row * D_);
  float4 v = xr[t];
  float s = v.x + v.y + v.z + v.w;
  float q = v.x * v.x + v.y * v.y + v.z * v.z + v.w * v.w;
#pragma unroll
  for (int off = 1; off < 64; off <<= 1) {
    s += __shfl_xor(s, off);
    q += __shfl_xor(q, off);
  }
  __shared__ float red[8];
  if (lane == 0) { red[wid] = s; red[4 + wid] = q; }
  __syncthreads();
  s = red[0] + red[1] + red[2] + red[3];
  q = red[4] + red[5] + red[6] + red[7];
  float mu = s * (1.0f / D_);
  float var = q * (1.0f / D_) - mu * mu;
  float rs = rsqrtf(var + EPS_);
  int c = t * 4;
  float4 wv = *(const float4*)(w + c);
  float4 bv = *(const float4*)(b + c);
  us4 o;
  o[0] = f2bf((v.x - mu) * rs * wv.x + bv.x);
  o[1] = f2bf((v.y - mu) * rs * wv.y + bv.y);
  o[2] = f2bf((v.z - mu) * rs * wv.z + bv.z);
  o[3] = f2bf((v.w - mu) * rs * wv.w + bv.w);
  *(us4*)(out + (size_t)row * D_ + c) = o;
}

// ---------------- GEMM 128x128 (m97 regime, proven ~880 TF) --------------------------------
// MODE bits: 1=bias, 2=gelu, 4=residual(f32), 8=bf16 out
template <int MODE>
__global__ __launch_bounds__(256) void gemm_kernel(
    const u16* __restrict__ A, const u16* __restrict__ Bt,
    const float* __restrict__ bias, const float* __restrict__ res,
    float* __restrict__ Cf, u16* __restrict__ Cb,
    int M, int N, int K) {
  __shared__ __align__(16) u16 Al[128 * 64];
  __shared__ __align__(16) u16 Bl[128 * 64];
  int t = threadIdx.x;
  int nbn = N >> 7;
  int nwg = gridDim.x, cpx = nwg >> 3;
  int bid = (blockIdx.x & 7) * cpx + (blockIdx.x >> 3);
  int nsn = nbn >> 3;
  int st = bid >> 6, u = bid & 63;
  int bm = (st / nsn) * 8 + (u >> 3);
  int bn = (st % nsn) * 8 + (u & 7);
  int lane = t & 63, wid = t >> 6;
  int wm = wid >> 1, wn = wid & 1;
  int lrow = lane & 15, lgr = lane >> 4;
  int sl7 = lrow & 7;
  const u16* Ab = A + (size_t)bm * 128 * K;
  const u16* Bb = Bt + (size_t)bn * 128 * K;
  int sr = lane >> 3;
  int sc = ((lane & 7) ^ sr) << 3;
  const u16* Ag[4];
  const u16* Bg[4];
  u16* Ald[4];
  u16* Bld[4];
#pragma unroll
  for (int j = 0; j < 4; j++) {
    int row0 = (j * 4 + wid) * 8;
    Ag[j] = Ab + (size_t)(row0 + sr) * K + sc;
    Bg[j] = Bb + (size_t)(row0 + sr) * K + sc;
    Ald[j] = &Al[row0 * 64 + lane * 8];
    Bld[j] = &Bl[row0 * 64 + lane * 8];
  }
  f32x4 acc[4][4] = {};
  for (int k0 = 0; k0 < K; k0 += 64) {
#pragma unroll
    for (int j = 0; j < 4; j++) {
      gl_lds16(Ag[j] + k0, Ald[j]);
      gl_lds16(Bg[j] + k0, Bld[j]);
    }
    __syncthreads();
    bf16x8 af[2][4], bfr[2][4];
#pragma unroll
    for (int ks = 0; ks < 2; ks++) {
      int slot = ((ks << 2) | lgr) ^ sl7;
#pragma unroll
      for (int m = 0; m < 4; m++)
        af[ks][m] = *(const bf16x8*)&Al[(wm * 64 + m * 16 + lrow) * 64 + slot * 8];
#pragma unroll
      for (int n = 0; n < 4; n++)
        bfr[ks][n] = *(const bf16x8*)&Bl[(wn * 64 + n * 16 + lrow) * 64 + slot * 8];
    }
    __builtin_amdgcn_s_setprio(1);
#pragma unroll
    for (int m = 0; m < 4; m++)
#pragma unroll
      for (int n = 0; n < 4; n++) {
        acc[m][n] = __builtin_amdgcn_mfma_f32_16x16x32_bf16(af[0][m], bfr[0][n], acc[m][n], 0, 0, 0);
        acc[m][n] = __builtin_amdgcn_mfma_f32_16x16x32_bf16(af[1][m], bfr[1][n], acc[m][n], 0, 0, 0);
      }
    __builtin_amdgcn_s_setprio(0);
    __syncthreads();
  }
#pragma unroll
  for (int n = 0; n < 4; n++) {
    int col = bn * 128 + wn * 64 + n * 16 + lrow;
    float bv = (MODE & 1) ? bias[col] : 0.0f;
#pragma unroll
    for (int m = 0; m < 4; m++)
#pragma unroll
      for (int r = 0; r < 4; r++) {
        int row = bm * 128 + wm * 64 + m * 16 + lgr * 4 + r;
        float v = acc[m][n][r] + bv;
        if (MODE & 2) v = gelu_f(v);
        if (MODE & 4) v += res[(size_t)row * N + col];
        if (MODE & 8) Cb[(size_t)row * N + col] = f2bf(v);
        else          Cf[(size_t)row * N + col] = v;
      }
  }
}

// ---------------- GEMM 8-phase, operand reuse, UNPINNED (m141 fix) -------------------------
// Identical sync structure to the r12 kernel that passed (absmax 0.03125), but all
// sched_barrier(0) pinning removed except the single rule-#18 fence after lgkmcnt(0).
// m141 evidence: sched_barrier(0)-pinned schedules collapse to ~510 TF; unpinned 8-phase
// (m198) reaches 1167 TF. Waits unchanged: (4,4,-,4) BM256 / (2,3,-,3) BM128.
#define VWAIT(n) asm volatile("s_waitcnt vmcnt(" #n ")" ::: "memory")

#define LDA(AF, MQ)                                                             \
  _Pragma("unroll") for (int ks = 0; ks < 2; ks++) {                            \
    int slot = ((((ks << 2) | lgr) ^ sl7)) * 8;                                 \
    _Pragma("unroll") for (int m = 0; m < MH; m++)                              \
      AF[ks][m] = *(const bf16x8*)&Ac[((MQ) * (BM / 2) + wm * (BM / 4) +        \
                                       m * 16 + lrow) * 64 + slot];             \
  }

#define LDB(BF, NQ)                                                             \
  _Pragma("unroll") for (int ks = 0; ks < 2; ks++) {                            \
    int slot = ((((ks << 2) | lgr) ^ sl7)) * 8;                                 \
    _Pragma("unroll") for (int nn = 0; nn < 2; nn++)                            \
      BF[ks][nn] = *(const bf16x8*)&Bc[((NQ) * 128 + wn * 32 + nn * 16 +        \
                                        lrow) * 64 + slot];                     \
  }

#define BARR_MFMA(MQ, NQ, AF, BF)                                               \
  __builtin_amdgcn_s_barrier();                                                 \
  asm volatile("s_waitcnt lgkmcnt(0)" ::: "memory");                            \
  __builtin_amdgcn_sched_barrier(0);                                            \
  __builtin_amdgcn_s_setprio(1);                                                \
  _Pragma("unroll") for (int m = 0; m < MH; m++)                                \
    _Pragma("unroll") for (int nn = 0; nn < 2; nn++) {                          \
      acc[MQ][NQ][m][nn] = __builtin_amdgcn_mfma_f32_16x16x32_bf16(             \
          AF[0][m], BF[0][nn], acc[MQ][NQ][m][nn], 0, 0, 0);                    \
      acc[MQ][NQ][m][nn] = __builtin_amdgcn_mfma_f32_16x16x32_bf16(             \
          AF[1][m], BF[1][nn], acc[MQ][NQ][m][nn], 0, 0, 0);                    \
    }                                                                           \
  __builtin_amdgcn_s_setprio(0);                                                \
  __builtin_amdgcn_s_barrier();

template <int MODE, int BM>
__global__ __launch_bounds__(512) void gemm8p_kernel(
    const u16* __restrict__ A, const u16* __restrict__ Bt,
    const float* __restrict__ bias, const float* __restrict__ res,
    float* __restrict__ Cf, u16* __restrict__ Cb,
    int M, int N, int K) {
  constexpr int LA = BM / 128;
  constexpr int MH = BM / 64;
  constexpr int ASZ = BM * 64;
  constexpr int BSZ = 256 * 64;
  extern __shared__ __align__(16) u16 sm[];
  int t = threadIdx.x;
  int nbn = N >> 8;
  int nwg = gridDim.x, cpx = nwg >> 3;
  int bid = (blockIdx.x % 8) * cpx + blockIdx.x / 8;
  int bm = bid / nbn, bn = bid % nbn;
  int lane = t & 63, wid = t >> 6;
  int wm = wid >> 2, wn = wid & 3;
  int lrow = lane & 15, lgr = lane >> 4;
  int sl7 = lrow & 7;
  const u16* Ab = A + (size_t)bm * BM * K;
  const u16* Bb = Bt + (size_t)bn * 256 * K;
  int srt = t >> 3;
  int ssc = (((t & 7) ^ (srt & 7)) << 3);
  const u16* Asrc = Ab + (size_t)srt * K + ssc;
  const u16* Bsrc = Bb + (size_t)srt * K + ssc;

  auto stageA = [&](int kt, int bsel, int h) {
    int k0 = kt * 64;
    u16* dst = sm + bsel * (ASZ + BSZ) + (h * (BM / 2)) * 64 + t * 8;
#pragma unroll
    for (int a = 0; a < LA; a++)
      gl_lds16(Asrc + (size_t)(h * (BM / 2) + a * 64) * K + k0, dst + a * 4096);
  };
  auto stageB = [&](int kt, int bsel, int h) {
    int k0 = kt * 64;
    u16* dst = sm + bsel * (ASZ + BSZ) + ASZ + (h * 128) * 64 + t * 8;
#pragma unroll
    for (int b2 = 0; b2 < 2; b2++)
      gl_lds16(Bsrc + (size_t)(h * 128 + b2 * 64) * K + k0, dst + b2 * 4096);
  };

  f32x4 acc[2][2][MH][2] = {};
  int NT = K >> 6;
  // prologue: tile 0 into buf 0, queue order [A0,B0,B1,A1]; wait THEN barrier
  stageA(0, 0, 0);
  stageB(0, 0, 0);
  stageB(0, 0, 1);
  stageA(0, 0, 1);
  if constexpr (BM == 256) VWAIT(4); else VWAIT(3);
  __builtin_amdgcn_s_barrier();
  for (int kt = 0; kt < NT - 1; kt++) {
    int cur = kt & 1, nb = cur ^ 1;
    const u16* Ac = sm + cur * (ASZ + BSZ);
    const u16* Bc = Ac + ASZ;
    bf16x8 af[2][MH], bf[2][2];
    // ph1 (0,0)
    LDA(af, 0);
    LDB(bf, 0);
    stageA(kt + 1, nb, 0);
    if constexpr (BM == 256) VWAIT(4); else VWAIT(2);   // guards B1(kt)
    BARR_MFMA(0, 0, af, bf);
    // ph2 (0,1): reuse af(A0)
    LDB(bf, 1);
    stageB(kt + 1, nb, 0);
    if constexpr (BM == 256) VWAIT(4); else VWAIT(3);   // guards A1(kt)
    BARR_MFMA(0, 1, af, bf);
    // ph3 (1,1): reuse bf(B1)
    LDA(af, 1);
    stageB(kt + 1, nb, 1);
    BARR_MFMA(1, 1, af, bf);
    // ph4 (1,0): reuse af(A1)
    LDB(bf, 0);
    stageA(kt + 1, nb, 1);
    if constexpr (BM == 256) VWAIT(4); else VWAIT(3);   // guards A0,B0(kt+1)
    BARR_MFMA(1, 0, af, bf);
  }
  {
    int cur = (NT - 1) & 1;
    const u16* Ac = sm + cur * (ASZ + BSZ);
    const u16* Bc = Ac + ASZ;
    bf16x8 af[2][MH], bf[2][2];
    LDA(af, 0);
    LDB(bf, 0);
    if constexpr (BM == 256) VWAIT(2); else VWAIT(1);   // guards B1(last)
    BARR_MFMA(0, 0, af, bf);
    LDB(bf, 1);
    VWAIT(0);                                           // guards A1(last)
    BARR_MFMA(0, 1, af, bf);
    LDA(af, 1);
    BARR_MFMA(1, 1, af, bf);
    LDB(bf, 0);
    BARR_MFMA(1, 0, af, bf);
  }
#pragma unroll
  for (int nq = 0; nq < 2; nq++) {
#pragma unroll
    for (int nn = 0; nn < 2; nn++) {
      int col = bn * 256 + nq * 128 + wn * 32 + nn * 16 + lrow;
      float bv = (MODE & 1) ? bias[col] : 0.0f;
#pragma unroll
      for (int mq = 0; mq < 2; mq++)
#pragma unroll
        for (int m = 0; m < MH; m++)
#pragma unroll
          for (int r = 0; r < 4; r++) {
            int row = bm * BM + mq * (BM / 2) + wm * (BM / 4) + m * 16 + lgr * 4 + r;
            float v = acc[mq][nq][m][nn][r] + bv;
            if (MODE & 2) v = gelu_f(v);
            if (MODE & 4) v += res[(size_t)row * N + col];
            if (MODE & 8) Cb[(size_t)row * N + col] = f2bf(v);
            else          Cf[(size_t)row * N + col] = v;
          }
    }
  }
}

// ---------------- attention helpers -------------------------------------------------------
__device__ __forceinline__ void attn_softmax_update(
    f32x16* s, int NSUB_rt, float& mrun, float& lrun, f32x16 (&o)[2], int hi) {
  float pmax = -3.0e38f;
  for (int sub = 0; sub < NSUB_rt; sub++)
#pragma unroll
    for (int r = 0; r < 16; r++) pmax = fmaxf(pmax, s[sub][r]);
  pmax = fmaxf(pmax, __shfl_xor(pmax, 32));
  bool ok = (pmax * SCALE_ <= mrun + THR_);
  if (!__all(ok)) {
    float mnew = fmaxf(mrun, pmax * SCALE_);
    float corr = __builtin_amdgcn_exp2f(mrun - mnew);
    mrun = mnew;
    lrun *= corr;
#pragma unroll
    for (int r = 0; r < 16; r++) {
      float cr = __shfl(corr, ((r & 3) + 8 * (r >> 2)) + 4 * hi);
      o[0][r] *= cr;
      o[1][r] *= cr;
    }
  }
  float m = mrun;
  float lacc = 0.f;
  for (int sub = 0; sub < NSUB_rt; sub++)
#pragma unroll
    for (int r = 0; r < 16; r++) {
      float p = __builtin_amdgcn_exp2f(__builtin_fmaf(s[sub][r], SCALE_, -m));
      s[sub][r] = p;
      lacc += p;
    }
  lrun += lacc;
}

__device__ __forceinline__ void attn_pfrag(const f32x16& s, bf16x8& pa, bf16x8& pb) {
  u32 a0 = cvtpk_bf16(s[0], s[1]);
  u32 a1 = cvtpk_bf16(s[2], s[3]);
  u32 a2 = cvtpk_bf16(s[4], s[5]);
  u32 a3 = cvtpk_bf16(s[6], s[7]);
  swap32(a0, a2);
  swap32(a1, a3);
  u32 b0 = cvtpk_bf16(s[8], s[9]);
  u32 b1 = cvtpk_bf16(s[10], s[11]);
  u32 b2 = cvtpk_bf16(s[12], s[13]);
  u32 b3 = cvtpk_bf16(s[14], s[15]);
  swap32(b0, b2);
  swap32(b1, b3);
  u32x4 fa = {a0, a1, a2, a3};
  u32x4 fb = {b0, b1, b2, b3};
  pa = __builtin_bit_cast(bf16x8, fa);
  pb = __builtin_bit_cast(bf16x8, fb);
}

template <bool MASK>
__device__ __forceinline__ void attn_chunk_tail(
    const u16* __restrict__ Kh, const u16* __restrict__ Vh,
    const bf16x8 (&qf)[4], f32x16 (&o)[2],
    float& mrun, float& lrun, int kb, int qrow, int hi, int ln31) {
  f32x16 s[1];
  f32x16 z = zero16();
  __builtin_amdgcn_s_setprio(1);
#pragma unroll
  for (int ks = 0; ks < 4; ks++) {
    bf16x8 kfr = *(const bf16x8*)(Kh + (size_t)(kb + ln31) * QKS_ + ks * 16 + hi * 8);
    z = __builtin_amdgcn_mfma_f32_32x32x16_bf16(kfr, qf[ks], z, 0, 0, 0);
  }
  __builtin_amdgcn_s_setprio(0);
  if (MASK) {
#pragma unroll
    for (int r = 0; r < 16; r++) {
      int key = kb + (r & 3) + 8 * (r >> 2) + 4 * hi;
      if (key > qrow) z[r] = -3.0e38f;
    }
  }
  s[0] = z;
  attn_softmax_update(s, 1, mrun, lrun, o, hi);
  bf16x8 pa, pb;
  attn_pfrag(s[0], pa, pb);
  __builtin_amdgcn_s_setprio(1);
#pragma unroll
  for (int ht = 0; ht < 2; ht++) {
    const u16* vb = Vh + (size_t)(ht * 32 + ln31) * S_ + kb + hi * 8;
    bf16x8 v1 = *(const bf16x8*)(vb);
    bf16x8 v2 = *(const bf16x8*)(vb + 16);
    o[ht] = __builtin_amdgcn_mfma_f32_32x32x16_bf16(pa, v1, o[ht], 0, 0, 0);
    o[ht] = __builtin_amdgcn_mfma_f32_32x32x16_bf16(pb, v2, o[ht], 0, 0, 0);
  }
  __builtin_amdgcn_s_setprio(0);
}

// ---------------- causal flash attention: 4 waves/block (128 q rows), shared K/V LDS -------
__global__ __launch_bounds__(256) void attn_kernel(const u16* __restrict__ kqv,
                                                   const u16* __restrict__ Vt,
                                                   u16* __restrict__ ctx) {
  __shared__ __align__(16) u16 Kl[2][64 * 64];
  __shared__ __align__(16) u16 Vl[2][64 * 64];
  int t = threadIdx.x;
  int lane = t & 63, wid = t >> 6;
  int qblk = 15 - (int)(blockIdx.x >> 6);
  int bh = blockIdx.x & 63;
  int b = bh >> 4, h = bh & 15;
  const u16* Qh = kqv + (size_t)b * S_ * QKS_ + 1024 + h * 64;
  const u16* Kh = kqv + (size_t)b * S_ * QKS_ + h * 64;
  const u16* Vh = Vt + (size_t)bh * HD_ * S_;
  int qb = qblk * 128;
  int qbase = qb + wid * 32;
  int ln31 = lane & 31, hi = lane >> 5;
  int qrow = qbase + ln31;
  int l7 = ln31 & 7;

  int srow = t >> 3;
  int sslot = (t & 7) ^ (srow & 7);
  const u16* Ksrc = Kh + (size_t)srow * QKS_ + sslot * 8;
  const u16* Vsrc = Vh + (size_t)srow * S_ + sslot * 8;

  auto stageK = [&](int kb1, int buf) {
    gl_lds16(Ksrc + (size_t)kb1 * QKS_, &Kl[buf][t * 8]);
    gl_lds16(Ksrc + (size_t)(kb1 + 32) * QKS_, &Kl[buf][2048 + t * 8]);
  };
  auto stageV = [&](int kb1, int buf) {
    gl_lds16(Vsrc + kb1, &Vl[buf][t * 8]);
    gl_lds16(Vsrc + (size_t)32 * S_ + kb1, &Vl[buf][2048 + t * 8]);
  };

  bf16x8 qf[4];
#pragma unroll
  for (int ks = 0; ks < 4; ks++)
    qf[ks] = *(const bf16x8*)(Qh + (size_t)qrow * QKS_ + ks * 16 + hi * 8);

  f32x16 o[2] = {zero16(), zero16()};
  float mrun = -1.0e30f, lrun = 0.f;

  int nf64 = qbase >> 6;
  int NT = (qb >> 6) + 2;

  stageK(0, 0);
  stageV(0, 0);
  for (int kt = 0; kt < NT; kt++) {
    int cur = kt & 1;
    if (kt + 1 < NT) {
      int kb1 = (kt + 1) * 64;
      stageK(kb1, cur ^ 1);
      stageV(kb1, cur ^ 1);
      asm volatile("s_waitcnt vmcnt(4)" ::: "memory");
    } else {
      asm volatile("s_waitcnt vmcnt(0)" ::: "memory");
    }
    __builtin_amdgcn_sched_barrier(0);
    __builtin_amdgcn_s_barrier();
    __builtin_amdgcn_sched_barrier(0);
    if (kt < nf64) {
      const u16* Kc = &Kl[cur][0];
      const u16* Vc = &Vl[cur][0];
      f32x16 s[2];
#pragma unroll
      for (int sub = 0; sub < 2; sub++) {
        f32x16 z = zero16();
        __builtin_amdgcn_s_setprio(1);
#pragma unroll
        for (int ks = 0; ks < 4; ks++) {
          int kr = sub * 32 + ln31;
          int sl = (ks * 2 + hi) ^ l7;
          bf16x8 kfr = *(const bf16x8*)&Kc[kr * 64 + sl * 8];
          z = __builtin_amdgcn_mfma_f32_32x32x16_bf16(kfr, qf[ks], z, 0, 0, 0);
        }
        __builtin_amdgcn_s_setprio(0);
        s[sub] = z;
      }
      attn_softmax_update(s, 2, mrun, lrun, o, hi);
#pragma unroll
      for (int sub = 0; sub < 2; sub++) {
        bf16x8 pa, pb;
        attn_pfrag(s[sub], pa, pb);
        __builtin_amdgcn_s_setprio(1);
#pragma unroll
        for (int ht = 0; ht < 2; ht++) {
          int vr = ht * 32 + ln31;
          int s1 = (sub * 4 + hi) ^ (vr & 7);
          int s2 = (sub * 4 + hi + 2) ^ (vr & 7);
          bf16x8 v1 = *(const bf16x8*)&Vc[vr * 64 + s1 * 8];
          bf16x8 v2 = *(const bf16x8*)&Vc[vr * 64 + s2 * 8];
          o[ht] = __builtin_amdgcn_mfma_f32_32x32x16_bf16(pa, v1, o[ht], 0, 0, 0);
          o[ht] = __builtin_amdgcn_mfma_f32_32x32x16_bf16(pb, v2, o[ht], 0, 0, 0);
        }
        __builtin_amdgcn_s_setprio(0);
      }
    }
    __builtin_amdgcn_sched_barrier(0);
    __builtin_amdgcn_s_barrier();
    __builtin_amdgcn_sched_barrier(0);
  }

  if (qbase & 32)
    attn_chunk_tail<false>(Kh, Vh, qf, o, mrun, lrun, qbase - 32, qrow, hi, ln31);
  attn_chunk_tail<true>(Kh, Vh, qf, o, mrun, lrun, qbase, qrow, hi, ln31);

  float l = lrun + __shfl_xor(lrun, 32);
  float inv = 1.0f / l;
#pragma unroll
  for (int r = 0; r < 16; r++) {
    float invr = __shfl(inv, ((r & 3) + 8 * (r >> 2)) + 4 * hi);
    int q = qbase + (r & 3) + 8 * (r >> 2) + 4 * hi;
    size_t base = ((size_t)b * S_ + q) * D_ + h * HD_;
    ctx[base + ln31] = f2bf(o[0][r] * invr);
    ctx[base + 32 + ln31] = f2bf(o[1][r] * invr);
  }
}

extern "C" void kernel_launch(void* const* d_in, const int* in_sizes, int n_in,
                              void* d_out, int out_size, void* d_ws, size_t ws_size,
                              hipStream_t stream) {
  const float* x = (const float*)d_in[0];
  const float* ln1w = (const float*)d_in[1];
  const float* ln1b = (const float*)d_in[2];
  const float* wqkv = (const float*)d_in[3];
  const float* wproj = (const float*)d_in[4];
  const float* bproj = (const float*)d_in[5];
  const float* ln2w = (const float*)d_in[6];
  const float* ln2b = (const float*)d_in[7];
  const float* wff1 = (const float*)d_in[8];
  const float* bff1 = (const float*)d_in[9];
  const float* wff2 = (const float*)d_in[10];
  const float* bff2 = (const float*)d_in[11];

  char* ws = (char*)d_ws;
  u16* wqkvT = (u16*)(ws + 0);                 //  6 MB  [3072][1024] (rows permuted: K|Q|V)
  u16* wprojT = (u16*)(ws + 6291456);          //  2 MB
  u16* wff1T = (u16*)(ws + 8388608);           //  8 MB
  u16* wff2T = (u16*)(ws + 16777216);          //  8 MB
  u16* h1 = (u16*)(ws + 25165824);             // 16 MB; dead after QKV gemm
  u16* Vt = (u16*)(ws + 25165824);             // 16 MB  [bh][64][S]
  u16* kqv = (u16*)(ws + 41943040);            // 48 MB  [8192][3072] packed K|Q|V
  u16* ctx = (u16*)(ws + 92274688);            // 16 MB
  float* x1 = (float*)(ws + 109051904);        // 32 MB
  u16* h2 = (u16*)(ws + 142606336);            // 16 MB
  u16* g = (u16*)(ws + 25165824);              // 64 MB; overlays Vt/kqv
  float* outp = (float*)d_out;

  hipFuncSetAttribute((const void*)gemm8p_kernel<11, 256>,
                      hipFuncAttributeMaxDynamicSharedMemorySize, 131072);
  hipFuncSetAttribute((const void*)gemm8p_kernel<5, 128>,
                      hipFuncAttributeMaxDynamicSharedMemorySize, 98304);

  wconv_kernel<<<(1024 / 32) * (3072 / 32), 256, 0, stream>>>(wqkv, wqkvT, 1024, 3072, 1);
  wconv_kernel<<<(1024 / 32) * (1024 / 32), 256, 0, stream>>>(wproj, wprojT, 1024, 1024, 0);
  wconv_kernel<<<(1024 / 32) * (4096 / 32), 256, 0, stream>>>(wff1, wff1T, 1024, 4096, 0);
  wconv_kernel<<<(4096 / 32) * (1024 / 32), 256, 0, stream>>>(wff2, wff2T, 4096, 1024, 0);

  ln_kernel<<<8192, 256, 0, stream>>>(x, ln1w, ln1b, h1);
  // QKV: proven m97 kernel, grid 64*24=1536
  gemm_kernel<8><<<1536, 256, 0, stream>>>(h1, wqkvT, nullptr, nullptr, nullptr, kqv,
                                           8192, 3072, 1024);
  vtrans_kernel<<<64 * 32, 256, 0, stream>>>(kqv, Vt);
  attn_kernel<<<16 * 64, 256, 0, stream>>>(kqv, Vt, ctx);
  // proj: proven m97 kernel, grid 512
  gemm_kernel<5><<<512, 256, 0, stream>>>(ctx, wprojT, bproj, x, x1, nullptr,
                                          8192, 1024, 1024);
  ln_kernel<<<8192, 256, 0, stream>>>(x1, ln2w, ln2b, h2);
  // FF1: 8-phase UNPINNED (A/B test), 256x256 tiles, grid 32*16=512
  gemm8p_kernel<11, 256><<<512, 512, 131072, stream>>>(h2, wff1T, bff1, nullptr, nullptr, g,
                                                       8192, 4096, 1024);
  // FF2: 8-phase UNPINNED (A/B test), 128x256 tiles, grid 64*4=256 (K=4096)
  gemm8p_kernel<5, 128><<<256, 512, 98304, stream>>>(g, wff2T, bff2, x1, outp, nullptr,
                                                     8192, 1024, 4096);
}

// Round 18
// 337.830 us; speedup vs baseline: 1.0414x; 1.0414x over previous
//
#include <hip/hip_runtime.h>

typedef unsigned short u16;
typedef unsigned int u32;
typedef __bf16 bf16x8 __attribute__((ext_vector_type(8)));
typedef float f32x4 __attribute__((ext_vector_type(4)));
typedef float f32x16 __attribute__((ext_vector_type(16)));
typedef unsigned short us8 __attribute__((ext_vector_type(8)));
typedef unsigned short us4 __attribute__((ext_vector_type(4)));
typedef unsigned int u32x4 __attribute__((ext_vector_type(4)));

#define B_ 4
#define S_ 2048
#define D_ 1024
#define H_ 16
#define HD_ 64
#define QKS_ 3072  // row stride (elems) of the packed kqv buffer
#define EPS_ 1e-5f
#define SCALE_ (0.125f * 1.44269504088896341f)
#define THR_ 3.0f

__device__ __forceinline__ u16 f2bf(float f) {
  unsigned u = __builtin_bit_cast(unsigned, f);
  u = (u + 0x7FFFu + ((u >> 16) & 1u)) >> 16;
  return (u16)u;
}
__device__ __forceinline__ float bf2f(u16 v) {
  unsigned u = ((unsigned)v) << 16;
  return __builtin_bit_cast(float, u);
}

__device__ __forceinline__ float gelu_f(float x) {
  float u = x * (2.3022388f + 0.10294971f * x * x);
  float te = __builtin_amdgcn_exp2f(u);
  return x - x * __builtin_amdgcn_rcpf(1.0f + te);
}

typedef const __attribute__((address_space(1))) unsigned int* gp1;
typedef __attribute__((address_space(3))) unsigned int* lp3;
__device__ __forceinline__ void gl_lds16(const void* g, void* l) {
  __builtin_amdgcn_global_load_lds((gp1)(unsigned long long)g,
                                   (lp3)(unsigned int)(unsigned long long)l,
                                   16, 0, 0);
}

__device__ __forceinline__ u32 cvtpk_bf16(float lo, float hi) {
  u32 d;
  asm("v_cvt_pk_bf16_f32 %0, %1, %2" : "=v"(d) : "v"(lo), "v"(hi));
  return d;
}
__device__ __forceinline__ void swap32(u32& a, u32& b) {
  asm("v_permlane32_swap_b32 %0, %1" : "+v"(a), "+v"(b));
}

__device__ __forceinline__ f32x16 zero16() {
  f32x16 z;
#pragma unroll
  for (int i = 0; i < 16; i++) z[i] = 0.f;
  return z;
}

// ---------------- weight transpose + f32->bf16 convert: W[K][N] -> Wt[N'][K] ---------------
__global__ __launch_bounds__(256) void wconv_kernel(const float* __restrict__ W,
                                                    u16* __restrict__ Wt,
                                                    int Kd, int N, int perm) {
  __shared__ u16 tile[32][33];
  int bid = blockIdx.x;
  int nbn = N >> 5;
  int tk = bid / nbn, tn = bid % nbn;
  int tx = threadIdx.x & 31, ty = threadIdx.x >> 5;
#pragma unroll
  for (int i = 0; i < 4; i++) {
    int r = ty + i * 8;
    tile[r][tx] = f2bf(W[(size_t)(tk * 32 + r) * N + tn * 32 + tx]);
  }
  __syncthreads();
#pragma unroll
  for (int i = 0; i < 4; i++) {
    int r = ty + i * 8;
    int orow = tn * 32 + r;
    int prow = perm ? ((orow % 3) << 10) + orow / 3 : orow;
    Wt[(size_t)prow * Kd + tk * 32 + tx] = tile[tx][r];
  }
}

// ---------------- V transpose: kqv V-block -> Vt [bh][64][S] --------------------------------
__global__ __launch_bounds__(256) void vtrans_kernel(const u16* __restrict__ kqv,
                                                     u16* __restrict__ Vt) {
  __shared__ u16 tile[64][72];
  int bh = blockIdx.x >> 5;
  int sb = blockIdx.x & 31;
  int b = bh >> 4, h = bh & 15;
  const u16* src = kqv + ((size_t)(b * S_ + sb * 64)) * QKS_ + 2048 + h * 64;
  int r = threadIdx.x >> 2, c0 = (threadIdx.x & 3) * 16;
  *(us8*)&tile[r][c0] = *(const us8*)(src + (size_t)r * QKS_ + c0);
  *(us8*)&tile[r][c0 + 8] = *(const us8*)(src + (size_t)r * QKS_ + c0 + 8);
  __syncthreads();
  u16* dst = Vt + (size_t)bh * HD_ * S_ + sb * 64;
  int hd = threadIdx.x >> 2;
  int s0 = (threadIdx.x & 3) * 16;
  us8 a, bb;
#pragma unroll
  for (int j = 0; j < 8; j++) a[j] = tile[s0 + j][hd];
#pragma unroll
  for (int j = 0; j < 8; j++) bb[j] = tile[s0 + 8 + j][hd];
  *(us8*)(dst + (size_t)hd * S_ + s0) = a;
  *(us8*)(dst + (size_t)hd * S_ + s0 + 8) = bb;
}

// ---------------- LayerNorm: f32 in -> bf16 out ---------------------------------------------
__global__ __launch_bounds__(256) void ln_kernel(const float* __restrict__ x,
                                                 const float* __restrict__ w,
                                                 const float* __restrict__ b,
                                                 u16* __restrict__ out) {
  int row = blockIdx.x;
  int t = threadIdx.x;
  int lane = t & 63, wid = t >> 6;
  const float4* xr = (const float4*)(x + (size_t)row * D_);
  float4 v = xr[t];
  float s = v.x + v.y + v.z + v.w;
  float q = v.x * v.x + v.y * v.y + v.z * v.z + v.w * v.w;
#pragma unroll
  for (int off = 1; off < 64; off <<= 1) {
    s += __shfl_xor(s, off);
    q += __shfl_xor(q, off);
  }
  __shared__ float red[8];
  if (lane == 0) { red[wid] = s; red[4 + wid] = q; }
  __syncthreads();
  s = red[0] + red[1] + red[2] + red[3];
  q = red[4] + red[5] + red[6] + red[7];
  float mu = s * (1.0f / D_);
  float var = q * (1.0f / D_) - mu * mu;
  float rs = rsqrtf(var + EPS_);
  int c = t * 4;
  float4 wv = *(const float4*)(w + c);
  float4 bv = *(const float4*)(b + c);
  us4 o;
  o[0] = f2bf((v.x - mu) * rs * wv.x + bv.x);
  o[1] = f2bf((v.y - mu) * rs * wv.y + bv.y);
  o[2] = f2bf((v.z - mu) * rs * wv.z + bv.z);
  o[3] = f2bf((v.w - mu) * rs * wv.w + bv.w);
  *(us4*)(out + (size_t)row * D_ + c) = o;
}

// ---------------- LayerNorm: bf16 in -> bf16 out ---------------------------------------------
__global__ __launch_bounds__(256) void lnb_kernel(const u16* __restrict__ x,
                                                  const float* __restrict__ w,
                                                  const float* __restrict__ b,
                                                  u16* __restrict__ out) {
  int row = blockIdx.x;
  int t = threadIdx.x;
  int lane = t & 63, wid = t >> 6;
  us4 xv = *(const us4*)(x + (size_t)row * D_ + t * 4);
  float v0 = bf2f(xv[0]), v1 = bf2f(xv[1]), v2 = bf2f(xv[2]), v3 = bf2f(xv[3]);
  float s = v0 + v1 + v2 + v3;
  float q = v0 * v0 + v1 * v1 + v2 * v2 + v3 * v3;
#pragma unroll
  for (int off = 1; off < 64; off <<= 1) {
    s += __shfl_xor(s, off);
    q += __shfl_xor(q, off);
  }
  __shared__ float red[8];
  if (lane == 0) { red[wid] = s; red[4 + wid] = q; }
  __syncthreads();
  s = red[0] + red[1] + red[2] + red[3];
  q = red[4] + red[5] + red[6] + red[7];
  float mu = s * (1.0f / D_);
  float var = q * (1.0f / D_) - mu * mu;
  float rs = rsqrtf(var + EPS_);
  int c = t * 4;
  float4 wv = *(const float4*)(w + c);
  float4 bv = *(const float4*)(b + c);
  us4 o;
  o[0] = f2bf((v0 - mu) * rs * wv.x + bv.x);
  o[1] = f2bf((v1 - mu) * rs * wv.y + bv.y);
  o[2] = f2bf((v2 - mu) * rs * wv.z + bv.z);
  o[3] = f2bf((v3 - mu) * rs * wv.w + bv.w);
  *(us4*)(out + (size_t)row * D_ + c) = o;
}

// ---------------- GEMM 128x128 (m97 regime, proven ~880 TF) --------------------------------
// MODE bits: 1=bias, 2=gelu, 4=residual f32, 8=bf16 out, 32=residual bf16
template <int MODE>
__global__ __launch_bounds__(256) void gemm_kernel(
    const u16* __restrict__ A, const u16* __restrict__ Bt,
    const float* __restrict__ bias, const float* __restrict__ res,
    const u16* __restrict__ resb,
    float* __restrict__ Cf, u16* __restrict__ Cb,
    int M, int N, int K) {
  __shared__ __align__(16) u16 Al[128 * 64];
  __shared__ __align__(16) u16 Bl[128 * 64];
  int t = threadIdx.x;
  int nbn = N >> 7;
  int nwg = gridDim.x, cpx = nwg >> 3;
  int bid = (blockIdx.x & 7) * cpx + (blockIdx.x >> 3);
  int nsn = nbn >> 3;
  int st = bid >> 6, u = bid & 63;
  int bm = (st / nsn) * 8 + (u >> 3);
  int bn = (st % nsn) * 8 + (u & 7);
  int lane = t & 63, wid = t >> 6;
  int wm = wid >> 1, wn = wid & 1;
  int lrow = lane & 15, lgr = lane >> 4;
  int sl7 = lrow & 7;
  const u16* Ab = A + (size_t)bm * 128 * K;
  const u16* Bb = Bt + (size_t)bn * 128 * K;
  int sr = lane >> 3;
  int sc = ((lane & 7) ^ sr) << 3;
  const u16* Ag[4];
  const u16* Bg[4];
  u16* Ald[4];
  u16* Bld[4];
#pragma unroll
  for (int j = 0; j < 4; j++) {
    int row0 = (j * 4 + wid) * 8;
    Ag[j] = Ab + (size_t)(row0 + sr) * K + sc;
    Bg[j] = Bb + (size_t)(row0 + sr) * K + sc;
    Ald[j] = &Al[row0 * 64 + lane * 8];
    Bld[j] = &Bl[row0 * 64 + lane * 8];
  }
  f32x4 acc[4][4] = {};
  for (int k0 = 0; k0 < K; k0 += 64) {
#pragma unroll
    for (int j = 0; j < 4; j++) {
      gl_lds16(Ag[j] + k0, Ald[j]);
      gl_lds16(Bg[j] + k0, Bld[j]);
    }
    __syncthreads();
    bf16x8 af[2][4], bfr[2][4];
#pragma unroll
    for (int ks = 0; ks < 2; ks++) {
      int slot = ((ks << 2) | lgr) ^ sl7;
#pragma unroll
      for (int m = 0; m < 4; m++)
        af[ks][m] = *(const bf16x8*)&Al[(wm * 64 + m * 16 + lrow) * 64 + slot * 8];
#pragma unroll
      for (int n = 0; n < 4; n++)
        bfr[ks][n] = *(const bf16x8*)&Bl[(wn * 64 + n * 16 + lrow) * 64 + slot * 8];
    }
    __builtin_amdgcn_s_setprio(1);
#pragma unroll
    for (int m = 0; m < 4; m++)
#pragma unroll
      for (int n = 0; n < 4; n++) {
        acc[m][n] = __builtin_amdgcn_mfma_f32_16x16x32_bf16(af[0][m], bfr[0][n], acc[m][n], 0, 0, 0);
        acc[m][n] = __builtin_amdgcn_mfma_f32_16x16x32_bf16(af[1][m], bfr[1][n], acc[m][n], 0, 0, 0);
      }
    __builtin_amdgcn_s_setprio(0);
    __syncthreads();
  }
#pragma unroll
  for (int n = 0; n < 4; n++) {
    int col = bn * 128 + wn * 64 + n * 16 + lrow;
    float bv = (MODE & 1) ? bias[col] : 0.0f;
#pragma unroll
    for (int m = 0; m < 4; m++)
#pragma unroll
      for (int r = 0; r < 4; r++) {
        int row = bm * 128 + wm * 64 + m * 16 + lgr * 4 + r;
        float v = acc[m][n][r] + bv;
        if (MODE & 2) v = gelu_f(v);
        if (MODE & 4) v += res[(size_t)row * N + col];
        if (MODE & 32) v += bf2f(resb[(size_t)row * N + col]);
        if (MODE & 8) Cb[(size_t)row * N + col] = f2bf(v);
        else          Cf[(size_t)row * N + col] = v;
      }
  }
}

// ---------------- attention helpers -------------------------------------------------------
__device__ __forceinline__ void attn_softmax_update(
    f32x16* s, int NSUB_rt, float& mrun, float& lrun, f32x16 (&o)[2], int hi) {
  float pmax = -3.0e38f;
  for (int sub = 0; sub < NSUB_rt; sub++)
#pragma unroll
    for (int r = 0; r < 16; r++) pmax = fmaxf(pmax, s[sub][r]);
  pmax = fmaxf(pmax, __shfl_xor(pmax, 32));
  bool ok = (pmax * SCALE_ <= mrun + THR_);
  if (!__all(ok)) {
    float mnew = fmaxf(mrun, pmax * SCALE_);
    float corr = __builtin_amdgcn_exp2f(mrun - mnew);
    mrun = mnew;
    lrun *= corr;
#pragma unroll
    for (int r = 0; r < 16; r++) {
      float cr = __shfl(corr, ((r & 3) + 8 * (r >> 2)) + 4 * hi);
      o[0][r] *= cr;
      o[1][r] *= cr;
    }
  }
  float m = mrun;
  float lacc = 0.f;
  for (int sub = 0; sub < NSUB_rt; sub++)
#pragma unroll
    for (int r = 0; r < 16; r++) {
      float p = __builtin_amdgcn_exp2f(__builtin_fmaf(s[sub][r], SCALE_, -m));
      s[sub][r] = p;
      lacc += p;
    }
  lrun += lacc;
}

__device__ __forceinline__ void attn_pfrag(const f32x16& s, bf16x8& pa, bf16x8& pb) {
  u32 a0 = cvtpk_bf16(s[0], s[1]);
  u32 a1 = cvtpk_bf16(s[2], s[3]);
  u32 a2 = cvtpk_bf16(s[4], s[5]);
  u32 a3 = cvtpk_bf16(s[6], s[7]);
  swap32(a0, a2);
  swap32(a1, a3);
  u32 b0 = cvtpk_bf16(s[8], s[9]);
  u32 b1 = cvtpk_bf16(s[10], s[11]);
  u32 b2 = cvtpk_bf16(s[12], s[13]);
  u32 b3 = cvtpk_bf16(s[14], s[15]);
  swap32(b0, b2);
  swap32(b1, b3);
  u32x4 fa = {a0, a1, a2, a3};
  u32x4 fb = {b0, b1, b2, b3};
  pa = __builtin_bit_cast(bf16x8, fa);
  pb = __builtin_bit_cast(bf16x8, fb);
}

template <bool MASK>
__device__ __forceinline__ void attn_chunk_tail(
    const u16* __restrict__ Kh, const u16* __restrict__ Vh,
    const bf16x8 (&qf)[4], f32x16 (&o)[2],
    float& mrun, float& lrun, int kb, int qrow, int hi, int ln31) {
  f32x16 s[1];
  f32x16 z = zero16();
  __builtin_amdgcn_s_setprio(1);
#pragma unroll
  for (int ks = 0; ks < 4; ks++) {
    bf16x8 kfr = *(const bf16x8*)(Kh + (size_t)(kb + ln31) * QKS_ + ks * 16 + hi * 8);
    z = __builtin_amdgcn_mfma_f32_32x32x16_bf16(kfr, qf[ks], z, 0, 0, 0);
  }
  __builtin_amdgcn_s_setprio(0);
  if (MASK) {
#pragma unroll
    for (int r = 0; r < 16; r++) {
      int key = kb + (r & 3) + 8 * (r >> 2) + 4 * hi;
      if (key > qrow) z[r] = -3.0e38f;
    }
  }
  s[0] = z;
  attn_softmax_update(s, 1, mrun, lrun, o, hi);
  bf16x8 pa, pb;
  attn_pfrag(s[0], pa, pb);
  __builtin_amdgcn_s_setprio(1);
#pragma unroll
  for (int ht = 0; ht < 2; ht++) {
    const u16* vb = Vh + (size_t)(ht * 32 + ln31) * S_ + kb + hi * 8;
    bf16x8 v1 = *(const bf16x8*)(vb);
    bf16x8 v2 = *(const bf16x8*)(vb + 16);
    o[ht] = __builtin_amdgcn_mfma_f32_32x32x16_bf16(pa, v1, o[ht], 0, 0, 0);
    o[ht] = __builtin_amdgcn_mfma_f32_32x32x16_bf16(pb, v2, o[ht], 0, 0, 0);
  }
  __builtin_amdgcn_s_setprio(0);
}

// ---------------- causal flash attention: 4 waves/block (128 q rows), shared K/V LDS -------
__global__ __launch_bounds__(256) void attn_kernel(const u16* __restrict__ kqv,
                                                   const u16* __restrict__ Vt,
                                                   u16* __restrict__ ctx) {
  __shared__ __align__(16) u16 Kl[2][64 * 64];
  __shared__ __align__(16) u16 Vl[2][64 * 64];
  int t = threadIdx.x;
  int lane = t & 63, wid = t >> 6;
  int qblk = 15 - (int)(blockIdx.x >> 6);
  int bh = blockIdx.x & 63;
  int b = bh >> 4, h = bh & 15;
  const u16* Qh = kqv + (size_t)b * S_ * QKS_ + 1024 + h * 64;
  const u16* Kh = kqv + (size_t)b * S_ * QKS_ + h * 64;
  const u16* Vh = Vt + (size_t)bh * HD_ * S_;
  int qb = qblk * 128;
  int qbase = qb + wid * 32;
  int ln31 = lane & 31, hi = lane >> 5;
  int qrow = qbase + ln31;
  int l7 = ln31 & 7;

  int srow = t >> 3;
  int sslot = (t & 7) ^ (srow & 7);
  const u16* Ksrc = Kh + (size_t)srow * QKS_ + sslot * 8;
  const u16* Vsrc = Vh + (size_t)srow * S_ + sslot * 8;

  auto stageK = [&](int kb1, int buf) {
    gl_lds16(Ksrc + (size_t)kb1 * QKS_, &Kl[buf][t * 8]);
    gl_lds16(Ksrc + (size_t)(kb1 + 32) * QKS_, &Kl[buf][2048 + t * 8]);
  };
  auto stageV = [&](int kb1, int buf) {
    gl_lds16(Vsrc + kb1, &Vl[buf][t * 8]);
    gl_lds16(Vsrc + (size_t)32 * S_ + kb1, &Vl[buf][2048 + t * 8]);
  };

  bf16x8 qf[4];
#pragma unroll
  for (int ks = 0; ks < 4; ks++)
    qf[ks] = *(const bf16x8*)(Qh + (size_t)qrow * QKS_ + ks * 16 + hi * 8);

  f32x16 o[2] = {zero16(), zero16()};
  float mrun = -1.0e30f, lrun = 0.f;

  int nf64 = qbase >> 6;
  int NT = (qb >> 6) + 2;

  stageK(0, 0);
  stageV(0, 0);
  for (int kt = 0; kt < NT; kt++) {
    int cur = kt & 1;
    if (kt + 1 < NT) {
      int kb1 = (kt + 1) * 64;
      stageK(kb1, cur ^ 1);
      stageV(kb1, cur ^ 1);
      asm volatile("s_waitcnt vmcnt(4)" ::: "memory");
    } else {
      asm volatile("s_waitcnt vmcnt(0)" ::: "memory");
    }
    __builtin_amdgcn_sched_barrier(0);
    __builtin_amdgcn_s_barrier();
    __builtin_amdgcn_sched_barrier(0);
    if (kt < nf64) {
      const u16* Kc = &Kl[cur][0];
      const u16* Vc = &Vl[cur][0];
      f32x16 s[2];
#pragma unroll
      for (int sub = 0; sub < 2; sub++) {
        f32x16 z = zero16();
        __builtin_amdgcn_s_setprio(1);
#pragma unroll
        for (int ks = 0; ks < 4; ks++) {
          int kr = sub * 32 + ln31;
          int sl = (ks * 2 + hi) ^ l7;
          bf16x8 kfr = *(const bf16x8*)&Kc[kr * 64 + sl * 8];
          z = __builtin_amdgcn_mfma_f32_32x32x16_bf16(kfr, qf[ks], z, 0, 0, 0);
        }
        __builtin_amdgcn_s_setprio(0);
        s[sub] = z;
      }
      attn_softmax_update(s, 2, mrun, lrun, o, hi);
#pragma unroll
      for (int sub = 0; sub < 2; sub++) {
        bf16x8 pa, pb;
        attn_pfrag(s[sub], pa, pb);
        __builtin_amdgcn_s_setprio(1);
#pragma unroll
        for (int ht = 0; ht < 2; ht++) {
          int vr = ht * 32 + ln31;
          int s1 = (sub * 4 + hi) ^ (vr & 7);
          int s2 = (sub * 4 + hi + 2) ^ (vr & 7);
          bf16x8 v1 = *(const bf16x8*)&Vc[vr * 64 + s1 * 8];
          bf16x8 v2 = *(const bf16x8*)&Vc[vr * 64 + s2 * 8];
          o[ht] = __builtin_amdgcn_mfma_f32_32x32x16_bf16(pa, v1, o[ht], 0, 0, 0);
          o[ht] = __builtin_amdgcn_mfma_f32_32x32x16_bf16(pb, v2, o[ht], 0, 0, 0);
        }
        __builtin_amdgcn_s_setprio(0);
      }
    }
    __builtin_amdgcn_sched_barrier(0);
    __builtin_amdgcn_s_barrier();
    __builtin_amdgcn_sched_barrier(0);
  }

  if (qbase & 32)
    attn_chunk_tail<false>(Kh, Vh, qf, o, mrun, lrun, qbase - 32, qrow, hi, ln31);
  attn_chunk_tail<true>(Kh, Vh, qf, o, mrun, lrun, qbase, qrow, hi, ln31);

  float l = lrun + __shfl_xor(lrun, 32);
  float inv = 1.0f / l;
#pragma unroll
  for (int r = 0; r < 16; r++) {
    float invr = __shfl(inv, ((r & 3) + 8 * (r >> 2)) + 4 * hi);
    int q = qbase + (r & 3) + 8 * (r >> 2) + 4 * hi;
    size_t base = ((size_t)b * S_ + q) * D_ + h * HD_;
    ctx[base + ln31] = f2bf(o[0][r] * invr);
    ctx[base + 32 + ln31] = f2bf(o[1][r] * invr);
  }
}

extern "C" void kernel_launch(void* const* d_in, const int* in_sizes, int n_in,
                              void* d_out, int out_size, void* d_ws, size_t ws_size,
                              hipStream_t stream) {
  const float* x = (const float*)d_in[0];
  const float* ln1w = (const float*)d_in[1];
  const float* ln1b = (const float*)d_in[2];
  const float* wqkv = (const float*)d_in[3];
  const float* wproj = (const float*)d_in[4];
  const float* bproj = (const float*)d_in[5];
  const float* ln2w = (const float*)d_in[6];
  const float* ln2b = (const float*)d_in[7];
  const float* wff1 = (const float*)d_in[8];
  const float* bff1 = (const float*)d_in[9];
  const float* wff2 = (const float*)d_in[10];
  const float* bff2 = (const float*)d_in[11];

  char* ws = (char*)d_ws;
  u16* wqkvT = (u16*)(ws + 0);                 //  6 MB  [3072][1024] (rows permuted: K|Q|V)
  u16* wprojT = (u16*)(ws + 6291456);          //  2 MB
  u16* wff1T = (u16*)(ws + 8388608);           //  8 MB
  u16* wff2T = (u16*)(ws + 16777216);          //  8 MB
  u16* h1 = (u16*)(ws + 25165824);             // 16 MB; dead after QKV gemm
  u16* Vt = (u16*)(ws + 25165824);             // 16 MB  [bh][64][S]
  u16* kqv = (u16*)(ws + 41943040);            // 48 MB  [8192][3072] packed K|Q|V
  u16* ctx = (u16*)(ws + 92274688);            // 16 MB
  u16* x1b = (u16*)(ws + 109051904);           // 16 MB  [8192][1024] bf16 residual
  u16* h2 = (u16*)(ws + 142606336);            // 16 MB
  u16* g = (u16*)(ws + 25165824);              // 64 MB; overlays Vt/kqv
  float* outp = (float*)d_out;

  wconv_kernel<<<(1024 / 32) * (3072 / 32), 256, 0, stream>>>(wqkv, wqkvT, 1024, 3072, 1);
  wconv_kernel<<<(1024 / 32) * (1024 / 32), 256, 0, stream>>>(wproj, wprojT, 1024, 1024, 0);
  wconv_kernel<<<(1024 / 32) * (4096 / 32), 256, 0, stream>>>(wff1, wff1T, 1024, 4096, 0);
  wconv_kernel<<<(4096 / 32) * (1024 / 32), 256, 0, stream>>>(wff2, wff2T, 4096, 1024, 0);

  ln_kernel<<<8192, 256, 0, stream>>>(x, ln1w, ln1b, h1);
  // QKV: proven m97 kernel, grid 64*24=1536
  gemm_kernel<8><<<1536, 256, 0, stream>>>(h1, wqkvT, nullptr, nullptr, nullptr,
                                           nullptr, kqv, 8192, 3072, 1024);
  vtrans_kernel<<<64 * 32, 256, 0, stream>>>(kqv, Vt);
  attn_kernel<<<16 * 64, 256, 0, stream>>>(kqv, Vt, ctx);
  // proj: bias + residual(x, f32) -> x1b bf16 (halves residual-path HBM traffic)
  gemm_kernel<13><<<512, 256, 0, stream>>>(ctx, wprojT, bproj, x, nullptr,
                                           nullptr, x1b, 8192, 1024, 1024);
  lnb_kernel<<<8192, 256, 0, stream>>>(x1b, ln2w, ln2b, h2);
  // FF1: bias + gelu -> g bf16
  gemm_kernel<11><<<2048, 256, 0, stream>>>(h2, wff1T, bff1, nullptr, nullptr,
                                            nullptr, g, 8192, 4096, 1024);
  // FF2: bias + residual(x1b, bf16) -> out f32 (K=4096)
  gemm_kernel<33><<<512, 256, 0, stream>>>(g, wff2T, bff2, nullptr, x1b,
                                           outp, nullptr, 8192, 1024, 4096);
}